// Round 6
// baseline (1764.705 us; speedup 1.0000x reference)
//
#include <hip/hip_runtime.h>
#include <cmath>

#define KNN 20
#define NCAND 32
#define NPTS 4096
#define BATCH 2
#define SLOPE 0.2f
#define BNEPS 1e-5
#define GTK 16

static __device__ __host__ inline int imin(int a, int b) { return a < b ? a : b; }

// ---------------- utility kernels ----------------
// x (B,3,N) -> xb (B,N,3)
__global__ void xtrans_kernel(const float* __restrict__ x, float* __restrict__ xb) {
  int i = blockIdx.x * 256 + threadIdx.x;
  if (i < BATCH * 3 * NPTS) {
    int b = i / (3 * NPTS);
    int r = i - b * 3 * NPTS;
    int c = r / NPTS;
    int n = r - c * NPTS;
    xb[((size_t)b * NPTS + n) * 3 + c] = x[i];
  }
}

// w (O,I) -> wt (I,O)
__global__ void wtrans_kernel(const float* __restrict__ w, float* __restrict__ wt, int O, int I) {
  int i = blockIdx.x * 256 + threadIdx.x;
  if (i < O * I) {
    int o = i / I, j = i - o * I;
    wt[(size_t)j * O + o] = w[i];
  }
}

// W (O, 2C) -> U (C, 2O): U[j][o]=W[o][j]; U[j][O+o]=W[o][C+j]-W[o][j]
__global__ void uprep_kernel(const float* __restrict__ W, float* __restrict__ U, int O, int C) {
  int i = blockIdx.x * 256 + threadIdx.x;
  if (i < C * O) {
    int j = i / O, o = i - j * O;
    float w1 = W[(size_t)o * 2 * C + j];
    float w2 = W[(size_t)o * 2 * C + C + j];
    U[(size_t)j * 2 * O + o] = w1;
    U[(size_t)j * 2 * O + O + o] = w2 - w1;
  }
}

// squared norms per point (fp64 accumulate, fp32 store — candidate pass only)
__global__ void xx_kernel(const float* __restrict__ X, int stride, int C, float* __restrict__ xx) {
  int i = blockIdx.x * 256 + threadIdx.x;
  if (i < BATCH * NPTS) {
    const float* r = X + (size_t)i * stride;
    double s = 0.0;
    for (int c = 0; c < C; ++c) s += (double)r[c] * (double)r[c];
    xx[i] = (float)s;
  }
}

// ---------------- generic 128x128 fp32 GEMM, 8x8 micro ----------------
// C[M x N] = A[M x K] * (BT ? B[N x K]^T : B[K x N]); DIST epilogue: 2*acc - xxA[r] - xxB[c]
// k-major swizzled LDS: phys(row) = row + (row>>5)*4, line stride 144 floats.
template <bool BT, bool DIST>
__global__ __launch_bounds__(256) void gemm128(const float* __restrict__ A, int lda,
                                               const float* __restrict__ B, int ldb,
                                               float* __restrict__ C, int ldc, int K,
                                               const float* __restrict__ xxA,
                                               const float* __restrict__ xxB) {
  __shared__ __align__(16) float sA[GTK][144];
  __shared__ __align__(16) float sB[GTK][144];
  int t = threadIdx.x;
  int tx = t & 15, ty = t >> 4;
  int row0 = blockIdx.y * 128, col0 = blockIdx.x * 128;
  float acc[8][8] = {};

  for (int k0 = 0; k0 < K; k0 += GTK) {
    bool fast = (k0 + GTK <= K);
    // stage A (transpose to k-major)
    if (fast) {
#pragma unroll
      for (int it = 0; it < 2; ++it) {
        int i = t + it * 256;
        int r = i >> 2, q = i & 3;
        const float4 av = *(const float4*)&A[(size_t)(row0 + r) * lda + k0 + q * 4];
        int pr = r + ((r >> 5) << 2);
        sA[q * 4 + 0][pr] = av.x;
        sA[q * 4 + 1][pr] = av.y;
        sA[q * 4 + 2][pr] = av.z;
        sA[q * 4 + 3][pr] = av.w;
      }
    } else {
#pragma unroll
      for (int it = 0; it < 2; ++it) {
        int i = t + it * 256;
        int r = i >> 2, q = i & 3;
        int pr = r + ((r >> 5) << 2);
#pragma unroll
        for (int j = 0; j < 4; ++j) {
          int k = q * 4 + j;
          sA[k][pr] = (k0 + k < K) ? A[(size_t)(row0 + r) * lda + k0 + k] : 0.f;
        }
      }
    }
    // stage B
    if (BT) {
      if (fast) {
#pragma unroll
        for (int it = 0; it < 2; ++it) {
          int i = t + it * 256;
          int r = i >> 2, q = i & 3;
          const float4 bv = *(const float4*)&B[(size_t)(col0 + r) * ldb + k0 + q * 4];
          int pr = r + ((r >> 5) << 2);
          sB[q * 4 + 0][pr] = bv.x;
          sB[q * 4 + 1][pr] = bv.y;
          sB[q * 4 + 2][pr] = bv.z;
          sB[q * 4 + 3][pr] = bv.w;
        }
      } else {
#pragma unroll
        for (int it = 0; it < 2; ++it) {
          int i = t + it * 256;
          int r = i >> 2, q = i & 3;
          int pr = r + ((r >> 5) << 2);
#pragma unroll
          for (int j = 0; j < 4; ++j) {
            int k = q * 4 + j;
            sB[k][pr] = (k0 + k < K) ? B[(size_t)(col0 + r) * ldb + k0 + k] : 0.f;
          }
        }
      }
    } else {
#pragma unroll
      for (int it = 0; it < 2; ++it) {
        int i = t + it * 256;
        int k = i >> 5, nq = (i & 31) * 4;
        int pc = nq + ((nq >> 5) << 2);
        float4 bv = make_float4(0.f, 0.f, 0.f, 0.f);
        if (k0 + k < K) bv = *(const float4*)&B[(size_t)(k0 + k) * ldb + col0 + nq];
        *(float4*)&sB[k][pc] = bv;
      }
    }
    __syncthreads();
    int prA = ty * 8 + ((ty >> 2) << 2);
    int prB = tx * 8 + ((tx >> 2) << 2);
#pragma unroll
    for (int kk = 0; kk < GTK; ++kk) {
      float a[8], b[8];
      *(float4*)&a[0] = *(const float4*)&sA[kk][prA];
      *(float4*)&a[4] = *(const float4*)&sA[kk][prA + 4];
      *(float4*)&b[0] = *(const float4*)&sB[kk][prB];
      *(float4*)&b[4] = *(const float4*)&sB[kk][prB + 4];
#pragma unroll
      for (int i = 0; i < 8; ++i)
#pragma unroll
        for (int j = 0; j < 8; ++j) acc[i][j] += a[i] * b[j];
    }
    __syncthreads();
  }

#pragma unroll
  for (int i = 0; i < 8; ++i) {
    int gr = row0 + ty * 8 + i;
    float xa = DIST ? xxA[gr] : 0.f;
#pragma unroll
    for (int jq = 0; jq < 2; ++jq) {
      float4 o;
#pragma unroll
      for (int j = 0; j < 4; ++j) {
        int gc = col0 + tx * 8 + jq * 4 + j;
        float v = acc[i][jq * 4 + j];
        ((float*)&o)[j] = DIST ? (2.f * v - xa - xxB[gc]) : v;
      }
      *(float4*)&C[(size_t)gr * ldc + col0 + tx * 8 + jq * 4] = o;
    }
  }
}

// ---------------- top-k: fp32 top-32 candidates, fp64 refine, exact top-20 ----------------
// One wave per row. dist rows are fp32 (candidate superset); final ranking is fp64 diff-form
// on the feature rows themselves -> matches the fp64 reference ranking.
__global__ __launch_bounds__(256) void topk_refine_kernel(const float* __restrict__ dist,
                                                          const float* __restrict__ Xb, int lda,
                                                          int C, int* __restrict__ idxout, int n0,
                                                          int rows) {
  int wave = threadIdx.x >> 6, lane = threadIdx.x & 63;
  int row = blockIdx.x * 4 + wave;
  if (row >= rows) return;
  const float* d = dist + (size_t)row * NPTS;
  float v[16][4];
#pragma unroll
  for (int s = 0; s < 16; ++s) *(float4*)v[s] = *(const float4*)&d[s * 256 + lane * 4];
  int base = lane * 4;
  int cm = 0;  // candidate held by lanes 0..NCAND-1
  for (int it = 0; it < NCAND; ++it) {
    float bv = v[0][0];
    int bi = base;
#pragma unroll
    for (int s = 0; s < 16; ++s)
#pragma unroll
      for (int c = 0; c < 4; ++c) {
        if (s == 0 && c == 0) continue;
        float x = v[s][c];
        if (x > bv) { bv = x; bi = s * 256 + base + c; }
      }
#pragma unroll
    for (int off = 1; off < 64; off <<= 1) {
      float ov = __shfl_xor(bv, off);
      int oi = __shfl_xor(bi, off);
      if (ov > bv || (ov == bv && oi < bi)) { bv = ov; bi = oi; }
    }
    if (it == lane) cm = bi;
#pragma unroll
    for (int s = 0; s < 16; ++s)
#pragma unroll
      for (int c = 0; c < 4; ++c)
        if (s * 256 + base + c == bi) v[s][c] = -__builtin_inff();
  }

  // fp64 refine: lanes l and l+32 each do half the channels of candidate l.
  int l = lane & 31;
  int half = lane >> 5;
  int m = __shfl(cm, l);
  int gn = n0 + row;
  int hc = (C + 1) >> 1;
  int c0 = half * hc;
  int c1 = imin(C, c0 + hc);
  double dd = 0.0;
  const float* crow = Xb + (size_t)gn * lda;
  const float* mrow = Xb + (size_t)m * lda;
  for (int c = c0; c < c1; ++c) {
    double diff = (double)crow[c] - (double)mrow[c];
    dd = fma(diff, diff, dd);
  }
  dd += __shfl_xor(dd, 32);  // lanes 0..31 now hold full sums
  double myval = (lane < NCAND) ? -dd : -__builtin_inf();
  int mym = (lane < NCAND) ? m : 0x7fffffff;

  // exact top-20 among 32 candidates; ties -> lower column index (lax.top_k semantics)
  for (int it = 0; it < KNN; ++it) {
    double rv = myval;
    int rm = mym;
#pragma unroll
    for (int off = 1; off < 64; off <<= 1) {
      double ov = __shfl_xor(rv, off);
      int oi = __shfl_xor(rm, off);
      if (ov > rv || (ov == rv && oi < rm)) { rv = ov; rm = oi; }
    }
    if (lane == 0) idxout[(size_t)gn * KNN + it] = rm;
    if (mym == rm) myval = -__builtin_inf();
  }
}

// ---------------- gather-max + per-block fp64 BN partial stats ----------------
// h[n,k,o] = P[idx[n,k],o] + Q[n,o]; PQ row = [P | Q] (stride 2O). One wave per point.
// Block partials (fp64) to pbuf[blk][2*O] = [sum | sumsq].
template <int NO>
__global__ __launch_bounds__(256) void gathermax_kernel(const float* __restrict__ PQ,
                                                        const int* __restrict__ idx,
                                                        float* __restrict__ hmax, int O,
                                                        double* __restrict__ pbuf) {
  __shared__ double sh1[4][256];
  __shared__ double sh2[4][256];
  int t = threadIdx.x;
  int wave = t >> 6, lane = t & 63;
  int pt = blockIdx.x * 4 + wave;
  int b = pt >> 12;
  int O2 = 2 * O;
  int iv = idx[(size_t)pt * KNN + (lane % KNN)];
  const float* Qp = PQ + (size_t)pt * O2 + O + lane * NO;
  float q[NO], mx[NO];
  double s1[NO], s2[NO];
#pragma unroll
  for (int c = 0; c < NO; ++c) {
    q[c] = Qp[c];
    mx[c] = -__builtin_inff();
    s1[c] = 0.0;
    s2[c] = 0.0;
  }
#pragma unroll
  for (int k = 0; k < KNN; ++k) {
    int m = __shfl(iv, k);
    const float* Pp = PQ + ((size_t)(b << 12) + m) * O2 + lane * NO;
    float p[NO];
#pragma unroll
    for (int c = 0; c < NO; ++c) p[c] = Pp[c];
#pragma unroll
    for (int c = 0; c < NO; ++c) {
      float h = p[c] + q[c];
      mx[c] = fmaxf(mx[c], h);
      double hd = (double)h;
      s1[c] += hd;
      s2[c] += hd * hd;
    }
  }
  float* Hp = hmax + (size_t)pt * O + lane * NO;
#pragma unroll
  for (int c = 0; c < NO; ++c) {
    Hp[c] = mx[c];
    sh1[wave][lane * NO + c] = s1[c];
    sh2[wave][lane * NO + c] = s2[c];
  }
  __syncthreads();
  if (t < O) {
    double a = 0.0, bb = 0.0;
#pragma unroll
    for (int w = 0; w < 4; ++w) {
      a += sh1[w][t];
      bb += sh2[w][t];
    }
    pbuf[(size_t)blockIdx.x * O2 + t] = a;
    pbuf[(size_t)blockIdx.x * O2 + O + t] = bb;
  }
}

// ---------------- deterministic parallel fp64 BN reduce + finalize ----------------
__global__ __launch_bounds__(256) void bn_reduce_finalize(const double* __restrict__ pbuf,
                                                          int nblk, int O,
                                                          const float* __restrict__ g,
                                                          const float* __restrict__ bb,
                                                          double invcount,
                                                          float* __restrict__ s_out,
                                                          float* __restrict__ t_out) {
  __shared__ double sh1[256];
  __shared__ double sh2[256];
  int o = blockIdx.x;
  int t = threadIdx.x;
  double s1 = 0.0, s2 = 0.0;
  for (int blk = t; blk < nblk; blk += 256) {
    s1 += pbuf[(size_t)blk * 2 * O + o];
    s2 += pbuf[(size_t)blk * 2 * O + O + o];
  }
  sh1[t] = s1;
  sh2[t] = s2;
  __syncthreads();
  for (int s = 128; s > 0; s >>= 1) {
    if (t < s) {
      sh1[t] += sh1[t + s];
      sh2[t] += sh2[t + s];
    }
    __syncthreads();
  }
  if (t == 0) {
    double mean = sh1[0] * invcount;
    double var = sh2[0] * invcount - mean * mean;
    double s = (double)g[o] / sqrt(var + BNEPS);
    s_out[o] = (float)s;
    t_out[o] = (float)((double)bb[o] - mean * s);
  }
}

// y = leaky(hmax*s+t) into feat column slice
__global__ void apply_kernel(const float* __restrict__ hmax, const float* __restrict__ s,
                             const float* __restrict__ tt, float* __restrict__ feat,
                             int colOff, int logO, int total) {
  int i = blockIdx.x * 256 + threadIdx.x;
  if (i >= total) return;
  int O = 1 << logO;
  int o = i & (O - 1);
  int pp = i >> logO;
  float v = hmax[i] * s[o] + tt[o];
  feat[(size_t)pp * 512 + colOff + o] = v > 0.f ? v : SLOPE * v;
}

// column partial stats over H (rows x 1024): pbuf[rb][2048] = [sum | sq] (fp64)
__global__ void colstats_kernel(const float* __restrict__ H, double* __restrict__ pbuf) {
  int o = blockIdx.x * 256 + threadIdx.x;
  int rb = blockIdx.y;
  int r0 = rb * 128;
  double s1 = 0.0, s2 = 0.0;
  for (int r = 0; r < 128; ++r) {
    double v = (double)H[(size_t)(r0 + r) * 1024 + o];
    s1 += v;
    s2 += v * v;
  }
  pbuf[(size_t)rb * 2048 + o] = s1;
  pbuf[(size_t)rb * 2048 + 1024 + o] = s2;
}

// out[b][o][n] = leaky(h5[b][n][o]*s+t)
__global__ void out_kernel(const float* __restrict__ h5, const float* __restrict__ s,
                           const float* __restrict__ tt, float* __restrict__ out) {
  __shared__ float tile[32][33];
  int b = blockIdx.z;
  int n0 = blockIdx.x * 32, o0 = blockIdx.y * 32;
  int t = threadIdx.x;
  for (int e = t; e < 1024; e += 256) {
    int rn = e >> 5, co = e & 31;
    int o = o0 + co;
    float v = h5[((size_t)b * NPTS + n0 + rn) * 1024 + o] * s[o] + tt[o];
    tile[rn][co] = v > 0.f ? v : SLOPE * v;
  }
  __syncthreads();
  for (int e = t; e < 1024; e += 256) {
    int ro = e >> 5, cn = e & 31;
    out[((size_t)b * 1024 + o0 + ro) * NPTS + n0 + cn] = tile[cn][ro];
  }
}

// ---------------- host ----------------
extern "C" void kernel_launch(void* const* d_in, const int* in_sizes, int n_in,
                              void* d_out, int out_size, void* d_ws, size_t ws_size,
                              hipStream_t stream) {
  const float* x = (const float*)d_in[0];
  const float* Wm[5] = {(const float*)d_in[1], (const float*)d_in[4], (const float*)d_in[7],
                        (const float*)d_in[10], (const float*)d_in[13]};
  const float* gv[5] = {(const float*)d_in[2], (const float*)d_in[5], (const float*)d_in[8],
                        (const float*)d_in[11], (const float*)d_in[14]};
  const float* bvv[5] = {(const float*)d_in[3], (const float*)d_in[6], (const float*)d_in[9],
                         (const float*)d_in[12], (const float*)d_in[15]};
  float* out = (float*)d_out;

  char* wsb = (char*)d_ws;
  size_t off = 0;
  auto alloc = [&](size_t bytes) -> char* {
    off = (off + 255) & ~(size_t)255;
    char* p = wsb + off;
    off += bytes;
    return p;
  };
  float* xb = (float*)alloc((size_t)BATCH * NPTS * 3 * 4);
  float* xxb = (float*)alloc((size_t)BATCH * NPTS * 4);
  int* idxb = (int*)alloc((size_t)BATCH * NPTS * KNN * 4);
  float* feat = (float*)alloc((size_t)BATCH * NPTS * 512 * 4);
  float* hmax = (float*)alloc((size_t)BATCH * NPTS * 256 * 4);
  float* h5 = (float*)alloc((size_t)BATCH * NPTS * 1024 * 4);
  float* PQ = h5;  // alias: PQ (<=8192x512) used per-layer, h5 only needed after
  float* U1 = (float*)alloc(3 * 128 * 4);
  float* U2 = (float*)alloc(64 * 128 * 4);
  float* U3 = (float*)alloc(64 * 256 * 4);
  float* U4 = (float*)alloc(128 * 512 * 4);
  float* w5t = (float*)alloc(512 * 1024 * 4);
  double* pbuf = (double*)alloc((size_t)2048 * 512 * 8);  // fp64 block partials (max O=256)
  float* stv = (float*)alloc(3072 * 4);
  off = (off + 255) & ~(size_t)255;
  size_t avail = (ws_size > off) ? (ws_size - off) : 0;
  size_t rmax = avail / ((size_t)NPTS * 4);
  int R;
  if (rmax >= NPTS) R = NPTS;
  else {
    R = (int)(rmax & ~(size_t)127);
    if (R < 128) R = 128;
  }
  float* distbuf = (float*)(wsb + off);

  float* sv[5] = {stv + 0, stv + 128, stv + 256, stv + 512, stv + 1024};
  float* tv[5] = {stv + 64, stv + 192, stv + 384, stv + 768, stv + 2048};
  float* Us[4] = {U1, U2, U3, U4};
  const int Cs[4] = {3, 64, 64, 128};
  const int Osz[4] = {64, 64, 128, 256};

  xtrans_kernel<<<(BATCH * 3 * NPTS + 255) / 256, 256, 0, stream>>>(x, xb);
  for (int l = 0; l < 4; ++l)
    uprep_kernel<<<(Cs[l] * Osz[l] + 255) / 256, 256, 0, stream>>>(Wm[l], Us[l], Osz[l], Cs[l]);
  wtrans_kernel<<<(1024 * 512 + 255) / 256, 256, 0, stream>>>(Wm[4], w5t, 1024, 512);

  auto knn = [&](const float* Xbase, int lda, int C) {
    xx_kernel<<<(BATCH * NPTS + 255) / 256, 256, 0, stream>>>(Xbase, lda, C, xxb);
    for (int b = 0; b < BATCH; ++b) {
      const float* Xb = Xbase + (size_t)b * NPTS * lda;
      for (int n0 = 0; n0 < NPTS; n0 += R) {
        int rows = imin(R, NPTS - n0);
        gemm128<true, true><<<dim3(NPTS / 128, rows / 128), 256, 0, stream>>>(
            Xb + (size_t)n0 * lda, lda, Xb, lda, distbuf, NPTS, C, xxb + (size_t)b * NPTS + n0,
            xxb + (size_t)b * NPTS);
        topk_refine_kernel<<<rows / 4, 256, 0, stream>>>(distbuf, Xb, lda, C,
                                                         idxb + (size_t)b * NPTS * KNN, n0, rows);
      }
    }
  };

  auto edge = [&](int li, const float* Xbase, int lda, int C, int O, int colOff) {
    knn(Xbase, lda, C);
    int O2 = 2 * O;
    gemm128<false, false><<<dim3(O2 / 128, BATCH * NPTS / 128), 256, 0, stream>>>(
        Xbase, lda, Us[li], O2, PQ, O2, C, nullptr, nullptr);
    int nblk = BATCH * NPTS / 4;
    if (O == 64)
      gathermax_kernel<1><<<nblk, 256, 0, stream>>>(PQ, idxb, hmax, O, pbuf);
    else if (O == 128)
      gathermax_kernel<2><<<nblk, 256, 0, stream>>>(PQ, idxb, hmax, O, pbuf);
    else
      gathermax_kernel<4><<<nblk, 256, 0, stream>>>(PQ, idxb, hmax, O, pbuf);
    bn_reduce_finalize<<<O, 256, 0, stream>>>(pbuf, nblk, O, gv[li], bvv[li],
                                              1.0 / ((double)BATCH * NPTS * KNN), sv[li], tv[li]);
    int logO = (O == 64) ? 6 : (O == 128) ? 7 : 8;
    int total = BATCH * NPTS * O;
    apply_kernel<<<(total + 255) / 256, 256, 0, stream>>>(hmax, sv[li], tv[li], feat, colOff, logO,
                                                          total);
  };

  edge(0, xb, 3, 3, 64, 0);
  edge(1, feat, 512, 64, 64, 64);
  edge(2, feat + 64, 512, 64, 128, 128);
  edge(3, feat + 128, 512, 128, 256, 256);

  gemm128<false, false><<<dim3(1024 / 128, BATCH * NPTS / 128), 256, 0, stream>>>(
      feat, 512, w5t, 1024, h5, 1024, 512, nullptr, nullptr);
  colstats_kernel<<<dim3(4, 64), 256, 0, stream>>>(h5, pbuf);
  bn_reduce_finalize<<<1024, 256, 0, stream>>>(pbuf, 64, 1024, gv[4], bvv[4],
                                               1.0 / ((double)BATCH * NPTS), sv[4], tv[4]);
  out_kernel<<<dim3(NPTS / 32, 1024 / 32, BATCH), 256, 0, stream>>>(h5, sv[4], tv[4], out);
}

// Round 7
// 926.150 us; speedup vs baseline: 1.9054x; 1.9054x over previous
//
#include <hip/hip_runtime.h>
#include <cmath>

#define KNN 20
#define NPTS 4096
#define BATCH 2
#define SLOPE 0.2f
#define BNEPS 1e-5
#define GTK 16
#define MAXCAND 256

static __device__ __host__ inline int imin(int a, int b) { return a < b ? a : b; }

// ---------------- utility kernels ----------------
// x (B,3,N) -> xb (B,N,3)
__global__ void xtrans_kernel(const float* __restrict__ x, float* __restrict__ xb) {
  int i = blockIdx.x * 256 + threadIdx.x;
  if (i < BATCH * 3 * NPTS) {
    int b = i / (3 * NPTS);
    int r = i - b * 3 * NPTS;
    int c = r / NPTS;
    int n = r - c * NPTS;
    xb[((size_t)b * NPTS + n) * 3 + c] = x[i];
  }
}

// w (O,I) -> wt (I,O)
__global__ void wtrans_kernel(const float* __restrict__ w, float* __restrict__ wt, int O, int I) {
  int i = blockIdx.x * 256 + threadIdx.x;
  if (i < O * I) {
    int o = i / I, j = i - o * I;
    wt[(size_t)j * O + o] = w[i];
  }
}

// W (O, 2C) -> U (C, 2O): U[j][o]=W[o][j]; U[j][O+o]=W[o][C+j]-W[o][j]
__global__ void uprep_kernel(const float* __restrict__ W, float* __restrict__ U, int O, int C) {
  int i = blockIdx.x * 256 + threadIdx.x;
  if (i < C * O) {
    int j = i / O, o = i - j * O;
    float w1 = W[(size_t)o * 2 * C + j];
    float w2 = W[(size_t)o * 2 * C + C + j];
    U[(size_t)j * 2 * O + o] = w1;
    U[(size_t)j * 2 * O + O + o] = w2 - w1;
  }
}

// squared norms per point (fp64 accumulate, fp32 store — candidate pass only)
__global__ void xx_kernel(const float* __restrict__ X, int stride, int C, float* __restrict__ xx) {
  int i = blockIdx.x * 256 + threadIdx.x;
  if (i < BATCH * NPTS) {
    const float* r = X + (size_t)i * stride;
    double s = 0.0;
    for (int c = 0; c < C; ++c) s += (double)r[c] * (double)r[c];
    xx[i] = (float)s;
  }
}

// ---------------- generic 128x128 fp32 GEMM, 8x8 micro ----------------
// C[M x N] = A[M x K] * (BT ? B[N x K]^T : B[K x N]); DIST epilogue: 2*acc - xxA[r] - xxB[c]
// k-major swizzled LDS: phys(row) = row + (row>>5)*4, line stride 144 floats.
template <bool BT, bool DIST>
__global__ __launch_bounds__(256) void gemm128(const float* __restrict__ A, int lda,
                                               const float* __restrict__ B, int ldb,
                                               float* __restrict__ C, int ldc, int K,
                                               const float* __restrict__ xxA,
                                               const float* __restrict__ xxB) {
  __shared__ __align__(16) float sA[GTK][144];
  __shared__ __align__(16) float sB[GTK][144];
  int t = threadIdx.x;
  int tx = t & 15, ty = t >> 4;
  int row0 = blockIdx.y * 128, col0 = blockIdx.x * 128;
  float acc[8][8] = {};

  for (int k0 = 0; k0 < K; k0 += GTK) {
    bool fast = (k0 + GTK <= K);
    // stage A (transpose to k-major)
    if (fast) {
#pragma unroll
      for (int it = 0; it < 2; ++it) {
        int i = t + it * 256;
        int r = i >> 2, q = i & 3;
        const float4 av = *(const float4*)&A[(size_t)(row0 + r) * lda + k0 + q * 4];
        int pr = r + ((r >> 5) << 2);
        sA[q * 4 + 0][pr] = av.x;
        sA[q * 4 + 1][pr] = av.y;
        sA[q * 4 + 2][pr] = av.z;
        sA[q * 4 + 3][pr] = av.w;
      }
    } else {
#pragma unroll
      for (int it = 0; it < 2; ++it) {
        int i = t + it * 256;
        int r = i >> 2, q = i & 3;
        int pr = r + ((r >> 5) << 2);
#pragma unroll
        for (int j = 0; j < 4; ++j) {
          int k = q * 4 + j;
          sA[k][pr] = (k0 + k < K) ? A[(size_t)(row0 + r) * lda + k0 + k] : 0.f;
        }
      }
    }
    // stage B
    if (BT) {
      if (fast) {
#pragma unroll
        for (int it = 0; it < 2; ++it) {
          int i = t + it * 256;
          int r = i >> 2, q = i & 3;
          const float4 bv = *(const float4*)&B[(size_t)(col0 + r) * ldb + k0 + q * 4];
          int pr = r + ((r >> 5) << 2);
          sB[q * 4 + 0][pr] = bv.x;
          sB[q * 4 + 1][pr] = bv.y;
          sB[q * 4 + 2][pr] = bv.z;
          sB[q * 4 + 3][pr] = bv.w;
        }
      } else {
#pragma unroll
        for (int it = 0; it < 2; ++it) {
          int i = t + it * 256;
          int r = i >> 2, q = i & 3;
          int pr = r + ((r >> 5) << 2);
#pragma unroll
          for (int j = 0; j < 4; ++j) {
            int k = q * 4 + j;
            sB[k][pr] = (k0 + k < K) ? B[(size_t)(col0 + r) * ldb + k0 + k] : 0.f;
          }
        }
      }
    } else {
#pragma unroll
      for (int it = 0; it < 2; ++it) {
        int i = t + it * 256;
        int k = i >> 5, nq = (i & 31) * 4;
        int pc = nq + ((nq >> 5) << 2);
        float4 bv = make_float4(0.f, 0.f, 0.f, 0.f);
        if (k0 + k < K) bv = *(const float4*)&B[(size_t)(k0 + k) * ldb + col0 + nq];
        *(float4*)&sB[k][pc] = bv;
      }
    }
    __syncthreads();
    int prA = ty * 8 + ((ty >> 2) << 2);
    int prB = tx * 8 + ((tx >> 2) << 2);
#pragma unroll
    for (int kk = 0; kk < GTK; ++kk) {
      float a[8], b[8];
      *(float4*)&a[0] = *(const float4*)&sA[kk][prA];
      *(float4*)&a[4] = *(const float4*)&sA[kk][prA + 4];
      *(float4*)&b[0] = *(const float4*)&sB[kk][prB];
      *(float4*)&b[4] = *(const float4*)&sB[kk][prB + 4];
#pragma unroll
      for (int i = 0; i < 8; ++i)
#pragma unroll
        for (int j = 0; j < 8; ++j) acc[i][j] += a[i] * b[j];
    }
    __syncthreads();
  }

#pragma unroll
  for (int i = 0; i < 8; ++i) {
    int gr = row0 + ty * 8 + i;
    float xa = DIST ? xxA[gr] : 0.f;
#pragma unroll
    for (int jq = 0; jq < 2; ++jq) {
      float4 o;
#pragma unroll
      for (int j = 0; j < 4; ++j) {
        int gc = col0 + tx * 8 + jq * 4 + j;
        float v = acc[i][jq * 4 + j];
        ((float*)&o)[j] = DIST ? (2.f * v - xa - xxB[gc]) : v;
      }
      *(float4*)&C[(size_t)gr * ldc + col0 + tx * 8 + jq * 4] = o;
    }
  }
}

// ---------------- fast top-k: threshold filter + fp64 rescore + bitonic sort ----------------
// One wave per row. T = 20th-largest lane-max guarantees >=20 pass and fp32-top-20 subset.
// Final ranking: exact fp64 diff-form distance, composite key (-d2, idx), lax.top_k order.
__device__ inline bool comp_less(double v, int i, double ov, int oi) {
  // ascending-by-value; equal values: larger index sorts "less" so that reading
  // descending gives ties -> lower index first (lax.top_k semantics)
  return (v < ov) || (v == ov && i > oi);
}

__global__ __launch_bounds__(256) void topk_fast_kernel(const float* __restrict__ dist,
                                                        const float* __restrict__ Xb, int lda,
                                                        int C, int* __restrict__ idxout, int n0,
                                                        int rows) {
  __shared__ int scand[4][MAXCAND];
  int wave = threadIdx.x >> 6, lane = threadIdx.x & 63;
  int row = blockIdx.x * 4 + wave;
  if (row >= rows) return;
  const float* d = dist + (size_t)row * NPTS;
  float v[16][4];
  float lmax = -__builtin_inff();
#pragma unroll
  for (int s = 0; s < 16; ++s) {
    *(float4*)v[s] = *(const float4*)&d[s * 256 + lane * 4];
#pragma unroll
    for (int c = 0; c < 4; ++c) lmax = fmaxf(lmax, v[s][c]);
  }

  // bitonic ascending sort of lane-maxes (values only) -> T at lane 44 (20th largest)
  float sv = lmax;
  for (int k = 2; k <= 64; k <<= 1) {
    for (int j = k >> 1; j > 0; j >>= 1) {
      float ov = __shfl_xor(sv, j);
      bool up = ((lane & k) == 0);
      bool lower = ((lane & j) == 0);
      bool mineLess = sv < ov;
      bool keepMine = (up == lower) ? mineLess : !mineLess;
      sv = keepMine ? sv : ov;
    }
  }
  float T = __shfl(sv, 44);

  // count passers and compact indices into per-wave LDS slab (deterministic order)
  int myCnt = 0;
#pragma unroll
  for (int s = 0; s < 16; ++s)
#pragma unroll
    for (int c = 0; c < 4; ++c) myCnt += (v[s][c] >= T) ? 1 : 0;
  int ofs = myCnt;
  for (int dlt = 1; dlt < 64; dlt <<= 1) {
    int o = __shfl_up(ofs, dlt);
    if (lane >= dlt) ofs += o;
  }
  int total = __shfl(ofs, 63);
  ofs -= myCnt;  // exclusive prefix
  int w = ofs;
#pragma unroll
  for (int s = 0; s < 16; ++s)
#pragma unroll
    for (int c = 0; c < 4; ++c) {
      if (v[s][c] >= T) {
        if (w < MAXCAND) scand[wave][w] = s * 256 + lane * 4 + c;
        ++w;
      }
    }
  int cnt = imin(total, MAXCAND);
  int gn = n0 + row;
  const float* crow = Xb + (size_t)gn * lda;
  int nch = (cnt + 63) >> 6;

  double runV = -__builtin_inf();
  int runI = 0x7fffffff;
  for (int ch = 0; ch < nch; ++ch) {
    int slot = ch * 64 + lane;
    int m = (slot < cnt) ? scand[wave][slot] : -1;
    double val = -__builtin_inf();
    int vi = 0x7fffffff;
    if (m >= 0) {
      const float* mrow = Xb + (size_t)m * lda;
      double dd = 0.0;
      if (C == 3) {
#pragma unroll
        for (int c = 0; c < 3; ++c) {
          double df = (double)crow[c] - (double)mrow[c];
          dd = fma(df, df, dd);
        }
      } else {
        for (int c = 0; c < C; c += 4) {
          float4 a = *(const float4*)&crow[c];
          float4 b = *(const float4*)&mrow[c];
#pragma unroll
          for (int q = 0; q < 4; ++q) {
            double df = (double)((const float*)&a)[q] - (double)((const float*)&b)[q];
            dd = fma(df, df, dd);
          }
        }
      }
      val = -dd;
      vi = m;
    }
    // bitonic ascending sort of this chunk by composite key
    for (int k = 2; k <= 64; k <<= 1) {
      for (int j = k >> 1; j > 0; j >>= 1) {
        double ov = __shfl_xor(val, j);
        int oi = __shfl_xor(vi, j);
        bool up = ((lane & k) == 0);
        bool lower = ((lane & j) == 0);
        bool mineLess = comp_less(val, vi, ov, oi);
        bool keepMine = (up == lower) ? mineLess : !mineLess;
        if (!keepMine) { val = ov; vi = oi; }
      }
    }
    if (ch == 0) {
      runV = val;
      runI = vi;
    } else {
      // merge: top-64 of (run asc, chunk asc): pairwise max with reversed chunk -> bitonic -> clean
      double rv = __shfl(val, 63 - lane);
      int ri = __shfl(vi, 63 - lane);
      if (comp_less(runV, runI, rv, ri)) { runV = rv; runI = ri; }
      for (int j = 32; j > 0; j >>= 1) {
        double ov = __shfl_xor(runV, j);
        int oi = __shfl_xor(runI, j);
        bool lower = ((lane & j) == 0);
        bool mineLess = comp_less(runV, runI, ov, oi);
        bool keepMine = lower ? mineLess : !mineLess;  // ascending clean
        if (!keepMine) { runV = ov; runI = oi; }
      }
    }
  }
  // ascending run: lane 63 = best. Emit top-20 in descending order.
  if (lane >= 44) idxout[(size_t)gn * KNN + (63 - lane)] = runI;
}

// ---------------- gather-max + per-block fp64 BN partial stats ----------------
// h[n,k,o] = P[idx[n,k],o] + Q[n,o]; PQ row = [P | Q] (stride 2O). One wave per point.
// Block partials (fp64) to pbuf[blk][2*O] = [sum | sumsq].
template <int NO>
__global__ __launch_bounds__(256) void gathermax_kernel(const float* __restrict__ PQ,
                                                        const int* __restrict__ idx,
                                                        float* __restrict__ hmax, int O,
                                                        double* __restrict__ pbuf) {
  __shared__ double sh1[4][256];
  __shared__ double sh2[4][256];
  int t = threadIdx.x;
  int wave = t >> 6, lane = t & 63;
  int pt = blockIdx.x * 4 + wave;
  int b = pt >> 12;
  int O2 = 2 * O;
  int iv = idx[(size_t)pt * KNN + (lane % KNN)];
  const float* Qp = PQ + (size_t)pt * O2 + O + lane * NO;
  float q[NO], mx[NO];
  double s1[NO], s2[NO];
#pragma unroll
  for (int c = 0; c < NO; ++c) {
    q[c] = Qp[c];
    mx[c] = -__builtin_inff();
    s1[c] = 0.0;
    s2[c] = 0.0;
  }
#pragma unroll
  for (int k = 0; k < KNN; ++k) {
    int m = __shfl(iv, k);
    const float* Pp = PQ + ((size_t)(b << 12) + m) * O2 + lane * NO;
    float p[NO];
#pragma unroll
    for (int c = 0; c < NO; ++c) p[c] = Pp[c];
#pragma unroll
    for (int c = 0; c < NO; ++c) {
      float h = p[c] + q[c];
      mx[c] = fmaxf(mx[c], h);
      double hd = (double)h;
      s1[c] += hd;
      s2[c] += hd * hd;
    }
  }
  float* Hp = hmax + (size_t)pt * O + lane * NO;
#pragma unroll
  for (int c = 0; c < NO; ++c) {
    Hp[c] = mx[c];
    sh1[wave][lane * NO + c] = s1[c];
    sh2[wave][lane * NO + c] = s2[c];
  }
  __syncthreads();
  if (t < O) {
    double a = 0.0, bb = 0.0;
#pragma unroll
    for (int w = 0; w < 4; ++w) {
      a += sh1[w][t];
      bb += sh2[w][t];
    }
    pbuf[(size_t)blockIdx.x * O2 + t] = a;
    pbuf[(size_t)blockIdx.x * O2 + O + t] = bb;
  }
}

// ---------------- deterministic parallel fp64 BN reduce + finalize ----------------
__global__ __launch_bounds__(256) void bn_reduce_finalize(const double* __restrict__ pbuf,
                                                          int nblk, int O,
                                                          const float* __restrict__ g,
                                                          const float* __restrict__ bb,
                                                          double invcount,
                                                          float* __restrict__ s_out,
                                                          float* __restrict__ t_out) {
  __shared__ double sh1[256];
  __shared__ double sh2[256];
  int o = blockIdx.x;
  int t = threadIdx.x;
  double s1 = 0.0, s2 = 0.0;
  for (int blk = t; blk < nblk; blk += 256) {
    s1 += pbuf[(size_t)blk * 2 * O + o];
    s2 += pbuf[(size_t)blk * 2 * O + O + o];
  }
  sh1[t] = s1;
  sh2[t] = s2;
  __syncthreads();
  for (int s = 128; s > 0; s >>= 1) {
    if (t < s) {
      sh1[t] += sh1[t + s];
      sh2[t] += sh2[t + s];
    }
    __syncthreads();
  }
  if (t == 0) {
    double mean = sh1[0] * invcount;
    double var = sh2[0] * invcount - mean * mean;
    double s = (double)g[o] / sqrt(var + BNEPS);
    s_out[o] = (float)s;
    t_out[o] = (float)((double)bb[o] - mean * s);
  }
}

// y = leaky(hmax*s+t) into feat column slice
__global__ void apply_kernel(const float* __restrict__ hmax, const float* __restrict__ s,
                             const float* __restrict__ tt, float* __restrict__ feat,
                             int colOff, int logO, int total) {
  int i = blockIdx.x * 256 + threadIdx.x;
  if (i >= total) return;
  int O = 1 << logO;
  int o = i & (O - 1);
  int pp = i >> logO;
  float v = hmax[i] * s[o] + tt[o];
  feat[(size_t)pp * 512 + colOff + o] = v > 0.f ? v : SLOPE * v;
}

// column partial stats over H (rows x 1024): pbuf[rb][2048] = [sum | sq] (fp64)
__global__ void colstats_kernel(const float* __restrict__ H, double* __restrict__ pbuf) {
  int o = blockIdx.x * 256 + threadIdx.x;
  int rb = blockIdx.y;
  int r0 = rb * 128;
  double s1 = 0.0, s2 = 0.0;
  for (int r = 0; r < 128; ++r) {
    double v = (double)H[(size_t)(r0 + r) * 1024 + o];
    s1 += v;
    s2 += v * v;
  }
  pbuf[(size_t)rb * 2048 + o] = s1;
  pbuf[(size_t)rb * 2048 + 1024 + o] = s2;
}

// out[b][o][n] = leaky(h5[b][n][o]*s+t)
__global__ void out_kernel(const float* __restrict__ h5, const float* __restrict__ s,
                           const float* __restrict__ tt, float* __restrict__ out) {
  __shared__ float tile[32][33];
  int b = blockIdx.z;
  int n0 = blockIdx.x * 32, o0 = blockIdx.y * 32;
  int t = threadIdx.x;
  for (int e = t; e < 1024; e += 256) {
    int rn = e >> 5, co = e & 31;
    int o = o0 + co;
    float v = h5[((size_t)b * NPTS + n0 + rn) * 1024 + o] * s[o] + tt[o];
    tile[rn][co] = v > 0.f ? v : SLOPE * v;
  }
  __syncthreads();
  for (int e = t; e < 1024; e += 256) {
    int ro = e >> 5, cn = e & 31;
    out[((size_t)b * 1024 + o0 + ro) * NPTS + n0 + cn] = tile[cn][ro];
  }
}

// ---------------- host ----------------
extern "C" void kernel_launch(void* const* d_in, const int* in_sizes, int n_in,
                              void* d_out, int out_size, void* d_ws, size_t ws_size,
                              hipStream_t stream) {
  const float* x = (const float*)d_in[0];
  const float* Wm[5] = {(const float*)d_in[1], (const float*)d_in[4], (const float*)d_in[7],
                        (const float*)d_in[10], (const float*)d_in[13]};
  const float* gv[5] = {(const float*)d_in[2], (const float*)d_in[5], (const float*)d_in[8],
                        (const float*)d_in[11], (const float*)d_in[14]};
  const float* bvv[5] = {(const float*)d_in[3], (const float*)d_in[6], (const float*)d_in[9],
                         (const float*)d_in[12], (const float*)d_in[15]};
  float* out = (float*)d_out;

  char* wsb = (char*)d_ws;
  size_t off = 0;
  auto alloc = [&](size_t bytes) -> char* {
    off = (off + 255) & ~(size_t)255;
    char* p = wsb + off;
    off += bytes;
    return p;
  };
  float* xb = (float*)alloc((size_t)BATCH * NPTS * 3 * 4);
  float* xxb = (float*)alloc((size_t)BATCH * NPTS * 4);
  int* idxb = (int*)alloc((size_t)BATCH * NPTS * KNN * 4);
  float* feat = (float*)alloc((size_t)BATCH * NPTS * 512 * 4);
  float* hmax = (float*)alloc((size_t)BATCH * NPTS * 256 * 4);
  float* h5 = (float*)alloc((size_t)BATCH * NPTS * 1024 * 4);
  float* PQ = h5;  // alias: PQ (<=8192x512) used per-layer, h5 only needed after
  float* U1 = (float*)alloc(3 * 128 * 4);
  float* U2 = (float*)alloc(64 * 128 * 4);
  float* U3 = (float*)alloc(64 * 256 * 4);
  float* U4 = (float*)alloc(128 * 512 * 4);
  float* w5t = (float*)alloc(512 * 1024 * 4);
  double* pbuf = (double*)alloc((size_t)2048 * 512 * 8);  // fp64 block partials (max O=256)
  float* stv = (float*)alloc(3072 * 4);
  off = (off + 255) & ~(size_t)255;
  size_t avail = (ws_size > off) ? (ws_size - off) : 0;
  size_t rmax = avail / ((size_t)NPTS * 4);
  int R;
  if (rmax >= NPTS) R = NPTS;
  else {
    R = (int)(rmax & ~(size_t)127);
    if (R < 128) R = 128;
  }
  float* distbuf = (float*)(wsb + off);

  float* sv[5] = {stv + 0, stv + 128, stv + 256, stv + 512, stv + 1024};
  float* tv[5] = {stv + 64, stv + 192, stv + 384, stv + 768, stv + 2048};
  float* Us[4] = {U1, U2, U3, U4};
  const int Cs[4] = {3, 64, 64, 128};
  const int Osz[4] = {64, 64, 128, 256};

  xtrans_kernel<<<(BATCH * 3 * NPTS + 255) / 256, 256, 0, stream>>>(x, xb);
  for (int l = 0; l < 4; ++l)
    uprep_kernel<<<(Cs[l] * Osz[l] + 255) / 256, 256, 0, stream>>>(Wm[l], Us[l], Osz[l], Cs[l]);
  wtrans_kernel<<<(1024 * 512 + 255) / 256, 256, 0, stream>>>(Wm[4], w5t, 1024, 512);

  auto knn = [&](const float* Xbase, int lda, int C) {
    xx_kernel<<<(BATCH * NPTS + 255) / 256, 256, 0, stream>>>(Xbase, lda, C, xxb);
    for (int b = 0; b < BATCH; ++b) {
      const float* Xb = Xbase + (size_t)b * NPTS * lda;
      for (int n0 = 0; n0 < NPTS; n0 += R) {
        int rows = imin(R, NPTS - n0);
        gemm128<true, true><<<dim3(NPTS / 128, rows / 128), 256, 0, stream>>>(
            Xb + (size_t)n0 * lda, lda, Xb, lda, distbuf, NPTS, C, xxb + (size_t)b * NPTS + n0,
            xxb + (size_t)b * NPTS);
        topk_fast_kernel<<<rows / 4, 256, 0, stream>>>(distbuf, Xb, lda, C,
                                                       idxb + (size_t)b * NPTS * KNN, n0, rows);
      }
    }
  };

  auto edge = [&](int li, const float* Xbase, int lda, int C, int O, int colOff) {
    knn(Xbase, lda, C);
    int O2 = 2 * O;
    gemm128<false, false><<<dim3(O2 / 128, BATCH * NPTS / 128), 256, 0, stream>>>(
        Xbase, lda, Us[li], O2, PQ, O2, C, nullptr, nullptr);
    int nblk = BATCH * NPTS / 4;
    if (O == 64)
      gathermax_kernel<1><<<nblk, 256, 0, stream>>>(PQ, idxb, hmax, O, pbuf);
    else if (O == 128)
      gathermax_kernel<2><<<nblk, 256, 0, stream>>>(PQ, idxb, hmax, O, pbuf);
    else
      gathermax_kernel<4><<<nblk, 256, 0, stream>>>(PQ, idxb, hmax, O, pbuf);
    bn_reduce_finalize<<<O, 256, 0, stream>>>(pbuf, nblk, O, gv[li], bvv[li],
                                              1.0 / ((double)BATCH * NPTS * KNN), sv[li], tv[li]);
    int logO = (O == 64) ? 6 : (O == 128) ? 7 : 8;
    int total = BATCH * NPTS * O;
    apply_kernel<<<(total + 255) / 256, 256, 0, stream>>>(hmax, sv[li], tv[li], feat, colOff, logO,
                                                          total);
  };

  edge(0, xb, 3, 3, 64, 0);
  edge(1, feat, 512, 64, 64, 64);
  edge(2, feat + 64, 512, 64, 128, 128);
  edge(3, feat + 128, 512, 128, 256, 256);

  gemm128<false, false><<<dim3(1024 / 128, BATCH * NPTS / 128), 256, 0, stream>>>(
      feat, 512, w5t, 1024, h5, 1024, 512, nullptr, nullptr);
  colstats_kernel<<<dim3(4, 64), 256, 0, stream>>>(h5, pbuf);
  bn_reduce_finalize<<<1024, 256, 0, stream>>>(pbuf, 64, 1024, gv[4], bvv[4],
                                               1.0 / ((double)BATCH * NPTS), sv[4], tv[4]);
  out_kernel<<<dim3(NPTS / 32, 1024 / 32, BATCH), 256, 0, stream>>>(h5, sv[4], tv[4], out);
}